// Round 5
// baseline (294.011 us; speedup 1.0000x reference)
//
#include <hip/hip_runtime.h>
#include <hip/hip_bf16.h>
#include <stdint.h>

#define NB 2
#define SEQ 1024
#define DMODEL 768
#define NH 12
#define DH 64
#define SCALE 0.125f

typedef __hip_bfloat16 bf16;
typedef __attribute__((ext_vector_type(8))) short short8;   // 8 x bf16 = 4 VGPRs
typedef __attribute__((ext_vector_type(4))) float f32x4;    // MFMA C/D

__device__ __forceinline__ float b2f(bf16 x){ return __bfloat162float(x); }
__device__ __forceinline__ bf16 f2b(float x){ return __float2bfloat16(x); }
__device__ __forceinline__ short f2bs(float x){
  bf16 h = __float2bfloat16(x); return *reinterpret_cast<short*>(&h);
}
__device__ __forceinline__ float s2f(short u){
  return __uint_as_float(((unsigned)(unsigned short)u) << 16);
}

// ---------------- f32 -> bf16 convert ----------------
__global__ __launch_bounds__(256) void cvt_kernel(const float* __restrict__ src,
                                                  bf16* __restrict__ dst, int n){
  int i = blockIdx.x*256 + threadIdx.x;
  if (i < n) dst[i] = f2b(src[i]);
}

// ---------------- LayerNorm: x[2048,768] f32 -> xn bf16 ----------------
__global__ __launch_bounds__(256) void ln_kernel(const float* __restrict__ x,
                                                 const float* __restrict__ g,
                                                 const float* __restrict__ bta,
                                                 bf16* __restrict__ xn){
  int row = blockIdx.x; int t = threadIdx.x;
  const float* xr = x + (size_t)row*DMODEL;
  float v0[3]; float s = 0.f, s2 = 0.f;
  #pragma unroll
  for (int i=0;i<3;i++){ float val = xr[t+256*i]; v0[i]=val; s+=val; s2+=val*val; }
  __shared__ float sb[256], s2b[256];
  sb[t]=s; s2b[t]=s2; __syncthreads();
  for (int off=128; off>0; off>>=1){
    if (t<off){ sb[t]+=sb[t+off]; s2b[t]+=s2b[t+off]; }
    __syncthreads();
  }
  float mean = sb[0]*(1.f/DMODEL);
  float var  = s2b[0]*(1.f/DMODEL) - mean*mean;
  float rstd = rsqrtf(var + 1e-5f);
  #pragma unroll
  for (int i=0;i<3;i++){
    int c = t+256*i;
    xn[(size_t)row*DMODEL + c] = f2b((v0[i]-mean)*rstd*g[c] + bta[c]);
  }
}

// ---------------- QKV GEMM (MFMA): xn[2048,768] @ wqkv^T -> q,k bf16 [b,h,n,d]; v -> vt [b,h,d,n] ----------------
__global__ __launch_bounds__(256) void gemm_qkv(const bf16* __restrict__ A,
                                                const bf16* __restrict__ W,
                                                bf16* __restrict__ q,
                                                bf16* __restrict__ k,
                                                bf16* __restrict__ vt){
  __shared__ bf16 As[128*32];
  __shared__ bf16 Bs[128*32];
  int n0 = blockIdx.x*128, m0 = blockIdx.y*128;
  int t = threadIdx.x, w = t>>6, lane = t&63;
  int ln16 = lane&15, q8 = (lane>>4)*8;
  int wm = w>>1, wn = w&1;
  f32x4 acc[4][4] = {};
  for (int k0=0; k0<768; k0+=32){
    __syncthreads();
    #pragma unroll
    for (int i=0;i<2;i++){
      int cc = t + i*256;
      int r = cc>>2, ko = (cc&3)*8;
      *(short8*)&As[r*32+ko] = *(const short8*)&A[(size_t)(m0+r)*768 + k0+ko];
      *(short8*)&Bs[r*32+ko] = *(const short8*)&W[(size_t)(n0+r)*768 + k0+ko];
    }
    __syncthreads();
    short8 af[4], bfr[4];
    #pragma unroll
    for (int mi=0;mi<4;mi++) af[mi]  = *(const short8*)&As[(wm*64+mi*16+ln16)*32 + q8];
    #pragma unroll
    for (int ni=0;ni<4;ni++) bfr[ni] = *(const short8*)&Bs[(wn*64+ni*16+ln16)*32 + q8];
    #pragma unroll
    for (int mi=0;mi<4;mi++)
      #pragma unroll
      for (int ni=0;ni<4;ni++)
        acc[mi][ni] = __builtin_amdgcn_mfma_f32_16x16x32_bf16(af[mi], bfr[ni], acc[mi][ni], 0, 0, 0);
  }
  int quad4 = (lane>>4)*4;
  #pragma unroll
  for (int mi=0;mi<4;mi++){
    #pragma unroll
    for (int ni=0;ni<4;ni++){
      int cg = n0 + wn*64 + ni*16 + ln16;
      int which = cg/768; int rem = cg - which*768;
      int h = rem>>6, dd = rem&63;
      #pragma unroll
      for (int r=0;r<4;r++){
        int m = m0 + wm*64 + mi*16 + quad4 + r;
        int bb = m>>10, n = m&1023;
        float val = acc[mi][ni][r];
        if (which==0)      q [((size_t)(bb*NH+h)*SEQ + n)*DH + dd] = f2b(val*SCALE);
        else if (which==1) k [((size_t)(bb*NH+h)*SEQ + n)*DH + dd] = f2b(val);
        else               vt[((size_t)(bb*NH+h)*DH + dd)*SEQ + n] = f2b(val);
      }
    }
  }
}

// ---------------- M = (-0.5*theta) @ gnn_w  (Tw+Tw^T == -1 identically) ----------------
__global__ __launch_bounds__(256) void mmat_kernel(const float* __restrict__ theta,
                                                   const float* __restrict__ gnn,
                                                   float* __restrict__ Mm){
  int t = threadIdx.x;
  if (t < 144){
    int i = t/12, kx = t%12;
    float sacc = 0.f;
    for (int j=0;j<12;j++) sacc += (-0.5f)*theta[i*12+j] * gnn[j*12+kx];
    Mm[t] = sacc;
  }
}

// ---------------- fused attention: QK^T -> softmax -> head-mix -> PV, no attn materialization ----------------
// grid (64 strips, 2 batches), 768 threads = 12 waves, wave h owns head h.
__global__ __launch_bounds__(768) void fused_attn(const bf16* __restrict__ q,
                                                  const bf16* __restrict__ k,
                                                  const bf16* __restrict__ vt,
                                                  const float* __restrict__ Mm,
                                                  bf16* __restrict__ aout){
  __shared__ bf16 attT[512*16];        // [pos 0..511][head 0..11, pad to 16]  16 KB
  __shared__ bf16 comb[12*16*36];      // [head][row 0..15][col 0..31, pad 36] 13.5 KB
  int b = blockIdx.y; int r0 = blockIdx.x*16;
  int t = threadIdx.x; int h = t>>6; int lane = t&63;
  int ln16 = lane&15, quad = lane>>4; int q8 = quad*8, quad4 = quad*4;
  const bf16* qB = q  + ((size_t)(b*NH+h)*SEQ)*DH;
  const bf16* kB = k  + ((size_t)(b*NH+h)*SEQ)*DH;
  const bf16* vB = vt + ((size_t)(b*NH+h)*DH)*SEQ;

  // zero attT pad columns (heads 12..15) once
  if (t < 512){
    attT[t*16+12] = f2b(0.f); attT[t*16+13] = f2b(0.f);
    attT[t*16+14] = f2b(0.f); attT[t*16+15] = f2b(0.f);
  }

  // mix A-frag: M[row=ln16][k=q8+j], zero-padded to 16x32
  short8 amix;
  #pragma unroll
  for (int j=0;j<8;j++){
    int kk = q8 + j;
    amix[j] = (ln16 < 12 && kk < 12) ? f2bs(Mm[ln16*12 + kk]) : (short)0;
  }

  // Q fragments for this head's 16 rows (reused everywhere)
  const bf16* qrow = qB + (size_t)(r0 + ln16)*DH;
  short8 aq0 = *(const short8*)(qrow + q8);
  short8 aq1 = *(const short8*)(qrow + 32 + q8);

  // ---- pass 1: row sums of exp(s) (no max-subtract; |s| ~ O(6) << 88) ----
  float l[4] = {0.f,0.f,0.f,0.f};
  for (int c0=0; c0<SEQ; c0+=16){
    const bf16* krow = kB + (size_t)(c0 + ln16)*DH;
    short8 bk0 = *(const short8*)(krow + q8);
    short8 bk1 = *(const short8*)(krow + 32 + q8);
    f32x4 a = {0.f,0.f,0.f,0.f};
    a = __builtin_amdgcn_mfma_f32_16x16x32_bf16(aq0, bk0, a, 0, 0, 0);
    a = __builtin_amdgcn_mfma_f32_16x16x32_bf16(aq1, bk1, a, 0, 0, 0);
    #pragma unroll
    for (int r=0;r<4;r++) l[r] += __expf(a[r]);
  }
  #pragma unroll
  for (int msk=1; msk<16; msk<<=1){
    #pragma unroll
    for (int r=0;r<4;r++) l[r] += __shfl_xor(l[r], msk);
  }
  float inv_l[4];
  #pragma unroll
  for (int r=0;r<4;r++) inv_l[r] = 1.0f/l[r];

  // ---- pass 2: per 32-col tile: attn -> LDS, MFMA head-mix, PV accumulate ----
  f32x4 oacc[4] = {};
  for (int it=0; it<32; it++){
    int c0 = it*32;
    // phase A: normalized attn tile -> attT[pos][h] bf16
    #pragma unroll
    for (int half=0; half<2; half++){
      int cc = c0 + half*16;
      const bf16* krow = kB + (size_t)(cc + ln16)*DH;
      short8 bk0 = *(const short8*)(krow + q8);
      short8 bk1 = *(const short8*)(krow + 32 + q8);
      f32x4 a = {0.f,0.f,0.f,0.f};
      a = __builtin_amdgcn_mfma_f32_16x16x32_bf16(aq0, bk0, a, 0, 0, 0);
      a = __builtin_amdgcn_mfma_f32_16x16x32_bf16(aq1, bk1, a, 0, 0, 0);
      #pragma unroll
      for (int r=0;r<4;r++){
        int pos = (quad4+r)*32 + half*16 + ln16;
        attT[pos*16 + h] = f2b(__expf(a[r])*inv_l[r]);
      }
    }
    __syncthreads();
    // phase B: comb = att + relu(M @ att) via MFMA; wave w does pos-tiles w, w+12, w+24
    for (int tile=h; tile<32; tile+=12){
      short8 bfr = {0,0,0,0,0,0,0,0};
      if (quad < 2) bfr = *(const short8*)&attT[(tile*16 + ln16)*16 + q8];
      f32x4 d = {0.f,0.f,0.f,0.f};
      d = __builtin_amdgcn_mfma_f32_16x16x32_bf16(amix, bfr, d, 0, 0, 0);
      if (quad < 3){
        #pragma unroll
        for (int rr=0; rr<4; rr++){
          int hh = quad4 + rr;                 // output head 0..11
          int pos = tile*16 + ln16;
          float av = b2f(attT[pos*16 + hh]);
          int r = pos>>5, c = pos&31;
          comb[(hh*16 + r)*36 + c] = f2b(av + fmaxf(d[rr], 0.f));
        }
      }
    }
    __syncthreads();
    // phase C: O += comb @ V  (A-frag from comb LDS, B-frags from vt in L2)
    short8 af = *(const short8*)&comb[(h*16 + ln16)*36 + q8];
    #pragma unroll
    for (int ni=0; ni<4; ni++){
      short8 bv = *(const short8*)&vB[(size_t)(ni*16 + ln16)*SEQ + c0 + q8];
      oacc[ni] = __builtin_amdgcn_mfma_f32_16x16x32_bf16(af, bv, oacc[ni], 0, 0, 0);
    }
  }
  // epilogue: O -> aout[b][n][h*64+d] bf16
  #pragma unroll
  for (int ni=0; ni<4; ni++)
    #pragma unroll
    for (int r=0; r<4; r++){
      int n = r0 + quad4 + r;
      aout[((size_t)b*SEQ + n)*DMODEL + h*DH + ni*16 + ln16] = f2b(oacc[ni][r]);
    }
}

// ---------------- out proj (MFMA): aout[2048,768] @ w_out^T + b_out -> f32 ----------------
__global__ __launch_bounds__(256) void gemm_out(const bf16* __restrict__ A,
                                                const bf16* __restrict__ W,
                                                const float* __restrict__ bias,
                                                float* __restrict__ out){
  __shared__ bf16 As[128*32];
  __shared__ bf16 Bs[128*32];
  int n0 = blockIdx.x*128, m0 = blockIdx.y*128;
  int t = threadIdx.x, w = t>>6, lane = t&63;
  int ln16 = lane&15, q8 = (lane>>4)*8;
  int wm = w>>1, wn = w&1;
  f32x4 acc[4][4] = {};
  for (int k0=0; k0<768; k0+=32){
    __syncthreads();
    #pragma unroll
    for (int i=0;i<2;i++){
      int cc = t + i*256;
      int r = cc>>2, ko = (cc&3)*8;
      *(short8*)&As[r*32+ko] = *(const short8*)&A[(size_t)(m0+r)*768 + k0+ko];
      *(short8*)&Bs[r*32+ko] = *(const short8*)&W[(size_t)(n0+r)*768 + k0+ko];
    }
    __syncthreads();
    short8 af[4], bfr[4];
    #pragma unroll
    for (int mi=0;mi<4;mi++) af[mi]  = *(const short8*)&As[(wm*64+mi*16+ln16)*32 + q8];
    #pragma unroll
    for (int ni=0;ni<4;ni++) bfr[ni] = *(const short8*)&Bs[(wn*64+ni*16+ln16)*32 + q8];
    #pragma unroll
    for (int mi=0;mi<4;mi++)
      #pragma unroll
      for (int ni=0;ni<4;ni++)
        acc[mi][ni] = __builtin_amdgcn_mfma_f32_16x16x32_bf16(af[mi], bfr[ni], acc[mi][ni], 0, 0, 0);
  }
  int quad4 = (lane>>4)*4;
  #pragma unroll
  for (int mi=0;mi<4;mi++)
    #pragma unroll
    for (int ni=0;ni<4;ni++){
      int cg = n0 + wn*64 + ni*16 + ln16;
      #pragma unroll
      for (int r=0;r<4;r++){
        int m = m0 + wm*64 + mi*16 + quad4 + r;
        out[(size_t)m*768 + cg] = acc[mi][ni][r] + bias[cg];
      }
    }
}

extern "C" void kernel_launch(void* const* d_in, const int* in_sizes, int n_in,
                              void* d_out, int out_size, void* d_ws, size_t ws_size,
                              hipStream_t stream){
  const float* x     = (const float*)d_in[0];
  const float* ln_g  = (const float*)d_in[1];
  const float* ln_b  = (const float*)d_in[2];
  const float* w_qkv = (const float*)d_in[3];
  const float* w_out = (const float*)d_in[4];
  const float* b_out = (const float*)d_in[5];
  const float* theta = (const float*)d_in[6];
  const float* gnn   = (const float*)d_in[7];
  float* out = (float*)d_out;

  char* p = (char*)d_ws;
  bf16* xnb   = (bf16*)p; p += (size_t)2048*768*2;
  bf16* wqkvb = (bf16*)p; p += (size_t)2304*768*2;
  bf16* woutb = (bf16*)p; p += (size_t)768*768*2;
  bf16* qb    = (bf16*)p; p += (size_t)NB*NH*SEQ*DH*2;
  bf16* kb    = (bf16*)p; p += (size_t)NB*NH*SEQ*DH*2;
  bf16* vtb   = (bf16*)p; p += (size_t)NB*NH*SEQ*DH*2;
  bf16* aoutb = (bf16*)p; p += (size_t)2048*768*2;
  float* Mm   = (float*)p;

  cvt_kernel<<<dim3((2304*768+255)/256), dim3(256), 0, stream>>>(w_qkv, wqkvb, 2304*768);
  cvt_kernel<<<dim3((768*768+255)/256),  dim3(256), 0, stream>>>(w_out, woutb, 768*768);
  ln_kernel<<<dim3(NB*SEQ), dim3(256), 0, stream>>>(x, ln_g, ln_b, xnb);
  mmat_kernel<<<dim3(1), dim3(256), 0, stream>>>(theta, gnn, Mm);
  gemm_qkv<<<dim3(18, 16), dim3(256), 0, stream>>>(xnb, wqkvb, qb, kb, vtb);
  fused_attn<<<dim3(64, NB), dim3(768), 0, stream>>>(qb, kb, vtb, Mm, aoutb);
  gemm_out<<<dim3(6, 16), dim3(256), 0, stream>>>(aoutb, woutb, b_out, out);
}

// Round 6
// 220.403 us; speedup vs baseline: 1.3340x; 1.3340x over previous
//
#include <hip/hip_runtime.h>
#include <hip/hip_bf16.h>
#include <stdint.h>

#define NB 2
#define SEQ 1024
#define DMODEL 768
#define NH 12
#define DH 64
#define SCALE 0.125f
#define NCH 4          // column chunks in fused attention

typedef __hip_bfloat16 bf16;
typedef __attribute__((ext_vector_type(8))) short short8;   // 8 x bf16 = 4 VGPRs
typedef __attribute__((ext_vector_type(4))) float f32x4;    // MFMA C/D

__device__ __forceinline__ float b2f(bf16 x){ return __bfloat162float(x); }
__device__ __forceinline__ bf16 f2b(float x){ return __float2bfloat16(x); }
__device__ __forceinline__ short f2bs(float x){
  bf16 h = __float2bfloat16(x); return *reinterpret_cast<short*>(&h);
}

// ---------------- f32 -> bf16 convert ----------------
__global__ __launch_bounds__(256) void cvt_kernel(const float* __restrict__ src,
                                                  bf16* __restrict__ dst, int n){
  int i = blockIdx.x*256 + threadIdx.x;
  if (i < n) dst[i] = f2b(src[i]);
}

// ---------------- LayerNorm: x[2048,768] f32 -> xn bf16 ----------------
__global__ __launch_bounds__(256) void ln_kernel(const float* __restrict__ x,
                                                 const float* __restrict__ g,
                                                 const float* __restrict__ bta,
                                                 bf16* __restrict__ xn){
  int row = blockIdx.x; int t = threadIdx.x;
  const float* xr = x + (size_t)row*DMODEL;
  float v0[3]; float s = 0.f, s2 = 0.f;
  #pragma unroll
  for (int i=0;i<3;i++){ float val = xr[t+256*i]; v0[i]=val; s+=val; s2+=val*val; }
  __shared__ float sb[256], s2b[256];
  sb[t]=s; s2b[t]=s2; __syncthreads();
  for (int off=128; off>0; off>>=1){
    if (t<off){ sb[t]+=sb[t+off]; s2b[t]+=s2b[t+off]; }
    __syncthreads();
  }
  float mean = sb[0]*(1.f/DMODEL);
  float var  = s2b[0]*(1.f/DMODEL) - mean*mean;
  float rstd = rsqrtf(var + 1e-5f);
  #pragma unroll
  for (int i=0;i<3;i++){
    int c = t+256*i;
    xn[(size_t)row*DMODEL + c] = f2b((v0[i]-mean)*rstd*g[c] + bta[c]);
  }
}

// ---------------- prep: block 0 computes M = (-0.5*theta)@gnn_w; blocks 1..96 zero l ----------------
__global__ __launch_bounds__(256) void prep_kernel(const float* __restrict__ theta,
                                                   const float* __restrict__ gnn,
                                                   float* __restrict__ Mm,
                                                   float* __restrict__ l){
  int bx = blockIdx.x, t = threadIdx.x;
  if (bx == 0){
    if (t < 144){
      int i = t/12, kx = t%12;
      float sacc = 0.f;
      for (int j=0;j<12;j++) sacc += (-0.5f)*theta[i*12+j] * gnn[j*12+kx];
      Mm[t] = sacc;
    }
  } else {
    l[(bx-1)*256 + t] = 0.f;      // 96*256 = 24576 = 2*12*1024
  }
}

// ---------------- QKV GEMM (MFMA): xn[2048,768] @ wqkv^T -> q,k bf16 [b,h,n,d]; v -> vt [b,h,d,n] ----------------
__global__ __launch_bounds__(256) void gemm_qkv(const bf16* __restrict__ A,
                                                const bf16* __restrict__ W,
                                                bf16* __restrict__ q,
                                                bf16* __restrict__ k,
                                                bf16* __restrict__ vt){
  __shared__ bf16 As[128*32];
  __shared__ bf16 Bs[128*32];
  int n0 = blockIdx.x*128, m0 = blockIdx.y*128;
  int t = threadIdx.x, w = t>>6, lane = t&63;
  int ln16 = lane&15, q8 = (lane>>4)*8;
  int wm = w>>1, wn = w&1;
  f32x4 acc[4][4] = {};
  for (int k0=0; k0<768; k0+=32){
    __syncthreads();
    #pragma unroll
    for (int i=0;i<2;i++){
      int cc = t + i*256;
      int r = cc>>2, ko = (cc&3)*8;
      *(short8*)&As[r*32+ko] = *(const short8*)&A[(size_t)(m0+r)*768 + k0+ko];
      *(short8*)&Bs[r*32+ko] = *(const short8*)&W[(size_t)(n0+r)*768 + k0+ko];
    }
    __syncthreads();
    short8 af[4], bfr[4];
    #pragma unroll
    for (int mi=0;mi<4;mi++) af[mi]  = *(const short8*)&As[(wm*64+mi*16+ln16)*32 + q8];
    #pragma unroll
    for (int ni=0;ni<4;ni++) bfr[ni] = *(const short8*)&Bs[(wn*64+ni*16+ln16)*32 + q8];
    #pragma unroll
    for (int mi=0;mi<4;mi++)
      #pragma unroll
      for (int ni=0;ni<4;ni++)
        acc[mi][ni] = __builtin_amdgcn_mfma_f32_16x16x32_bf16(af[mi], bfr[ni], acc[mi][ni], 0, 0, 0);
  }
  int quad4 = (lane>>4)*4;
  #pragma unroll
  for (int mi=0;mi<4;mi++){
    #pragma unroll
    for (int ni=0;ni<4;ni++){
      int cg = n0 + wn*64 + ni*16 + ln16;
      int which = cg/768; int rem = cg - which*768;
      int h = rem>>6, dd = rem&63;
      #pragma unroll
      for (int r=0;r<4;r++){
        int m = m0 + wm*64 + mi*16 + quad4 + r;
        int bb = m>>10, n = m&1023;
        float val = acc[mi][ni][r];
        if (which==0)      q [((size_t)(bb*NH+h)*SEQ + n)*DH + dd] = f2b(val*SCALE);
        else if (which==1) k [((size_t)(bb*NH+h)*SEQ + n)*DH + dd] = f2b(val);
        else               vt[((size_t)(bb*NH+h)*DH + dd)*SEQ + n] = f2b(val);
      }
    }
  }
}

// ---------------- pass 1 (col-chunked): l[b,h,n] += sum_chunk exp(s) ----------------
// grid (64 strips, NCH chunks, NB), 768 threads = 12 waves, wave h = head h.
__global__ __launch_bounds__(768) void attn_sums(const bf16* __restrict__ q,
                                                 const bf16* __restrict__ k,
                                                 float* __restrict__ l){
  int b = blockIdx.z, ch = blockIdx.y; int r0 = blockIdx.x*16;
  int t = threadIdx.x; int h = t>>6; int lane = t&63;
  int ln16 = lane&15, quad = lane>>4; int q8 = quad*8, quad4 = quad*4;
  const bf16* qrow = q + ((size_t)(b*NH+h)*SEQ + r0 + ln16)*DH;
  short8 aq0 = *(const short8*)(qrow + q8);
  short8 aq1 = *(const short8*)(qrow + 32 + q8);
  const bf16* kB = k + ((size_t)(b*NH+h)*SEQ)*DH;
  float ls[4] = {0.f,0.f,0.f,0.f};
  for (int i=0;i<16;i++){
    int c0 = ch*256 + i*16;
    const bf16* krow = kB + (size_t)(c0 + ln16)*DH;
    short8 bk0 = *(const short8*)(krow + q8);
    short8 bk1 = *(const short8*)(krow + 32 + q8);
    f32x4 a = {0.f,0.f,0.f,0.f};
    a = __builtin_amdgcn_mfma_f32_16x16x32_bf16(aq0, bk0, a, 0, 0, 0);
    a = __builtin_amdgcn_mfma_f32_16x16x32_bf16(aq1, bk1, a, 0, 0, 0);
    #pragma unroll
    for (int r=0;r<4;r++) ls[r] += __expf(a[r]);
  }
  #pragma unroll
  for (int msk=1; msk<16; msk<<=1){
    #pragma unroll
    for (int r=0;r<4;r++) ls[r] += __shfl_xor(ls[r], msk);
  }
  if (ln16 == 0){
    #pragma unroll
    for (int r=0;r<4;r++)
      atomicAdd(&l[((size_t)(b*NH+h))*SEQ + r0 + quad4 + r], ls[r]);
  }
}

// ---------------- pass 2 (col-chunked): scores->softmax->mix->PV partial ----------------
// grid (64 strips, NCH chunks, NB), 768 threads = 12 waves, wave h = head h.
__global__ __launch_bounds__(768) void attn_main(const bf16* __restrict__ q,
                                                 const bf16* __restrict__ k,
                                                 const bf16* __restrict__ vt,
                                                 const float* __restrict__ Mm,
                                                 const float* __restrict__ l,
                                                 float* __restrict__ opart){
  __shared__ bf16 attT[512*16];        // [pos 0..511][head, pad 16]  16 KB
  __shared__ bf16 comb[12*16*40];      // [head][row 0..15][col 0..31, pad 40] 15.4 KB
  int b = blockIdx.z, ch = blockIdx.y; int r0 = blockIdx.x*16;
  int t = threadIdx.x; int h = t>>6; int lane = t&63;
  int ln16 = lane&15, quad = lane>>4; int q8 = quad*8, quad4 = quad*4;
  const bf16* kB = k  + ((size_t)(b*NH+h)*SEQ)*DH;
  const bf16* vB = vt + ((size_t)(b*NH+h)*DH)*SEQ;

  // zero attT pad columns (heads 12..15) — persists, phase A only writes 0..11
  if (t < 512){
    attT[t*16+12] = f2b(0.f); attT[t*16+13] = f2b(0.f);
    attT[t*16+14] = f2b(0.f); attT[t*16+15] = f2b(0.f);
  }

  // mix A-frag: M[row=ln16][k=q8+j], zero-padded to 16x32
  short8 amix;
  #pragma unroll
  for (int j=0;j<8;j++){
    int kk = q8 + j;
    amix[j] = (ln16 < 12 && kk < 12) ? f2bs(Mm[ln16*12 + kk]) : (short)0;
  }

  // Q fragments for this head's 16 rows
  const bf16* qrow = q + ((size_t)(b*NH+h)*SEQ + r0 + ln16)*DH;
  short8 aq0 = *(const short8*)(qrow + q8);
  short8 aq1 = *(const short8*)(qrow + 32 + q8);

  // reciprocal denominators for this lane's 4 rows
  float inv_l[4];
  #pragma unroll
  for (int r=0;r<4;r++) inv_l[r] = 1.0f / l[((size_t)(b*NH+h))*SEQ + r0 + quad4 + r];

  f32x4 oacc[4] = {};
  for (int it=0; it<8; it++){
    int c0 = ch*256 + it*32;
    // phase A: normalized attn tile -> attT[pos][h]
    #pragma unroll
    for (int half=0; half<2; half++){
      int cc = c0 + half*16;
      const bf16* krow = kB + (size_t)(cc + ln16)*DH;
      short8 bk0 = *(const short8*)(krow + q8);
      short8 bk1 = *(const short8*)(krow + 32 + q8);
      f32x4 a = {0.f,0.f,0.f,0.f};
      a = __builtin_amdgcn_mfma_f32_16x16x32_bf16(aq0, bk0, a, 0, 0, 0);
      a = __builtin_amdgcn_mfma_f32_16x16x32_bf16(aq1, bk1, a, 0, 0, 0);
      #pragma unroll
      for (int r=0;r<4;r++){
        int pos = (quad4+r)*32 + half*16 + ln16;
        attT[pos*16 + h] = f2b(__expf(a[r])*inv_l[r]);
      }
    }
    __syncthreads();
    // phase B: comb = att + relu(M @ att) via MFMA over pos-16 tiles
    for (int tile=h; tile<32; tile+=12){
      short8 bfr = {0,0,0,0,0,0,0,0};
      if (quad < 2) bfr = *(const short8*)&attT[(tile*16 + ln16)*16 + q8];
      f32x4 d = {0.f,0.f,0.f,0.f};
      d = __builtin_amdgcn_mfma_f32_16x16x32_bf16(amix, bfr, d, 0, 0, 0);
      if (quad < 3){
        #pragma unroll
        for (int rr=0; rr<4; rr++){
          int hh = quad4 + rr;                 // output head 0..11
          int pos = tile*16 + ln16;
          float av = b2f(attT[pos*16 + hh]);
          int r = pos>>5, c = pos&31;
          comb[(hh*16 + r)*40 + c] = f2b(av + fmaxf(d[rr], 0.f));
        }
      }
    }
    __syncthreads();
    // phase C: O += comb @ V
    short8 af = *(const short8*)&comb[(h*16 + ln16)*40 + q8];
    #pragma unroll
    for (int ni=0; ni<4; ni++){
      short8 bv = *(const short8*)&vB[(size_t)(ni*16 + ln16)*SEQ + c0 + q8];
      oacc[ni] = __builtin_amdgcn_mfma_f32_16x16x32_bf16(af, bv, oacc[ni], 0, 0, 0);
    }
  }
  // epilogue: partial O (f32) for this chunk
  float* dst = opart + ((size_t)ch*NB*SEQ + (size_t)b*SEQ)*DMODEL;
  #pragma unroll
  for (int ni=0; ni<4; ni++)
    #pragma unroll
    for (int r=0; r<4; r++){
      int n = r0 + quad4 + r;
      dst[(size_t)n*DMODEL + h*DH + ni*16 + ln16] = oacc[ni][r];
    }
}

// ---------------- reduce partials: aout = bf16( sum_ch opart ) ----------------
__global__ __launch_bounds__(256) void reduce_kernel(const float* __restrict__ opart,
                                                     bf16* __restrict__ aout){
  const size_t TOT = (size_t)NB*SEQ*DMODEL;      // 1,572,864
  size_t i = ((size_t)blockIdx.x*256 + threadIdx.x)*4;
  float4 s = *(const float4*)&opart[i];
  #pragma unroll
  for (int c=1;c<NCH;c++){
    float4 p = *(const float4*)&opart[c*TOT + i];
    s.x += p.x; s.y += p.y; s.z += p.z; s.w += p.w;
  }
  aout[i+0]=f2b(s.x); aout[i+1]=f2b(s.y); aout[i+2]=f2b(s.z); aout[i+3]=f2b(s.w);
}

// ---------------- out proj (MFMA): aout[2048,768] @ w_out^T + b_out -> f32 ----------------
__global__ __launch_bounds__(256) void gemm_out(const bf16* __restrict__ A,
                                                const bf16* __restrict__ W,
                                                const float* __restrict__ bias,
                                                float* __restrict__ out){
  __shared__ bf16 As[128*32];
  __shared__ bf16 Bs[128*32];
  int n0 = blockIdx.x*128, m0 = blockIdx.y*128;
  int t = threadIdx.x, w = t>>6, lane = t&63;
  int ln16 = lane&15, q8 = (lane>>4)*8;
  int wm = w>>1, wn = w&1;
  f32x4 acc[4][4] = {};
  for (int k0=0; k0<768; k0+=32){
    __syncthreads();
    #pragma unroll
    for (int i=0;i<2;i++){
      int cc = t + i*256;
      int r = cc>>2, ko = (cc&3)*8;
      *(short8*)&As[r*32+ko] = *(const short8*)&A[(size_t)(m0+r)*768 + k0+ko];
      *(short8*)&Bs[r*32+ko] = *(const short8*)&W[(size_t)(n0+r)*768 + k0+ko];
    }
    __syncthreads();
    short8 af[4], bfr[4];
    #pragma unroll
    for (int mi=0;mi<4;mi++) af[mi]  = *(const short8*)&As[(wm*64+mi*16+ln16)*32 + q8];
    #pragma unroll
    for (int ni=0;ni<4;ni++) bfr[ni] = *(const short8*)&Bs[(wn*64+ni*16+ln16)*32 + q8];
    #pragma unroll
    for (int mi=0;mi<4;mi++)
      #pragma unroll
      for (int ni=0;ni<4;ni++)
        acc[mi][ni] = __builtin_amdgcn_mfma_f32_16x16x32_bf16(af[mi], bfr[ni], acc[mi][ni], 0, 0, 0);
  }
  int quad4 = (lane>>4)*4;
  #pragma unroll
  for (int mi=0;mi<4;mi++)
    #pragma unroll
    for (int ni=0;ni<4;ni++){
      int cg = n0 + wn*64 + ni*16 + ln16;
      #pragma unroll
      for (int r=0;r<4;r++){
        int m = m0 + wm*64 + mi*16 + quad4 + r;
        out[(size_t)m*768 + cg] = acc[mi][ni][r] + bias[cg];
      }
    }
}

extern "C" void kernel_launch(void* const* d_in, const int* in_sizes, int n_in,
                              void* d_out, int out_size, void* d_ws, size_t ws_size,
                              hipStream_t stream){
  const float* x     = (const float*)d_in[0];
  const float* ln_g  = (const float*)d_in[1];
  const float* ln_b  = (const float*)d_in[2];
  const float* w_qkv = (const float*)d_in[3];
  const float* w_out = (const float*)d_in[4];
  const float* b_out = (const float*)d_in[5];
  const float* theta = (const float*)d_in[6];
  const float* gnn   = (const float*)d_in[7];
  float* out = (float*)d_out;

  char* p = (char*)d_ws;
  bf16* xnb   = (bf16*)p; p += (size_t)2048*768*2;
  bf16* wqkvb = (bf16*)p; p += (size_t)2304*768*2;
  bf16* woutb = (bf16*)p; p += (size_t)768*768*2;
  bf16* qb    = (bf16*)p; p += (size_t)NB*NH*SEQ*DH*2;
  bf16* kb    = (bf16*)p; p += (size_t)NB*NH*SEQ*DH*2;
  bf16* vtb   = (bf16*)p; p += (size_t)NB*NH*SEQ*DH*2;
  bf16* aoutb = (bf16*)p; p += (size_t)2048*768*2;
  float* Mm   = (float*)p; p += 256*4;
  float* lsum = (float*)p; p += (size_t)NB*NH*SEQ*4;
  float* opart= (float*)p;                        // NCH * 2048*768 f32 = 25.2 MB

  cvt_kernel<<<dim3((2304*768+255)/256), dim3(256), 0, stream>>>(w_qkv, wqkvb, 2304*768);
  cvt_kernel<<<dim3((768*768+255)/256),  dim3(256), 0, stream>>>(w_out, woutb, 768*768);
  ln_kernel<<<dim3(NB*SEQ), dim3(256), 0, stream>>>(x, ln_g, ln_b, xnb);
  prep_kernel<<<dim3(97), dim3(256), 0, stream>>>(theta, gnn, Mm, lsum);
  gemm_qkv<<<dim3(18, 16), dim3(256), 0, stream>>>(xnb, wqkvb, qb, kb, vtb);
  attn_sums<<<dim3(64, NCH, NB), dim3(768), 0, stream>>>(qb, kb, lsum);
  attn_main<<<dim3(64, NCH, NB), dim3(768), 0, stream>>>(qb, kb, vtb, Mm, lsum, opart);
  reduce_kernel<<<dim3((NB*SEQ*DMODEL/4+255)/256), dim3(256), 0, stream>>>(opart, aoutb);
  gemm_out<<<dim3(6, 16), dim3(256), 0, stream>>>(aoutb, woutb, b_out, out);
}